// Round 1
// baseline (114.915 us; speedup 1.0000x reference)
//
#include <hip/hip_runtime.h>
#include <math.h>

// Problem constants (match reference)
#define N_CAM 2
#define PH 96
#define PW 144
#define NPTS 200
#define VD 32
#define VH 128
#define VW 384

constexpr float MIN_DEPTH = 1.0f;
constexpr float MAX_DEPTH = 4000.0f;
constexpr float EPS_T = 1e-10f;
constexpr float VOXEL = 2.5f;

#define SEG 8                       // segments (lanes) per ray
#define SAMP_PER_SEG (NPTS / SEG)   // 25
#define PIX_PER_BLOCK (256 / SEG)   // 32
#define TOTAL_PIX (N_CAM * PH * PW) // 27648

__device__ __forceinline__ float huber01(float diff) {
    // (sqrt(1 + diff^2/0.01) - 1) * 0.1 ; always >= 0 so |.| is a no-op
    float t = diff * 10.0f;
    return (sqrtf(fmaf(t, t, 1.0f)) - 1.0f) * 0.1f;
}

__global__ __launch_bounds__(256) void render_loss_kernel(
    const float* __restrict__ dens,      // [VD*VH*VW]
    const float* __restrict__ cols,      // [3*VD*VH*VW] planar
    const float* __restrict__ tsil,      // [N_CAM*PH*PW]
    const float* __restrict__ timg,      // [N_CAM*PH*PW*3]
    const float* __restrict__ focal,     // [N_CAM*2]
    const float* __restrict__ principal, // [N_CAM*2]
    const float* __restrict__ Rm,        // [N_CAM*9]
    const float* __restrict__ Tv,        // [N_CAM*3]
    float* __restrict__ ws)              // [0]=color_sum, [1]=sil_sum
{
    const int tid = threadIdx.x;
    const int seg = tid & (SEG - 1);
    const int pix = blockIdx.x * PIX_PER_BLOCK + (tid >> 3);

    const int n   = pix / (PH * PW);
    const int rem = pix - n * (PH * PW);
    const int h   = rem / PW;
    const int w   = rem - h * PW;

    // Ray setup (general R, T per reference formulas)
    const float dx = ((float)w + 0.5f - principal[n * 2 + 0]) / focal[n * 2 + 0];
    const float dy = ((float)h + 0.5f - principal[n * 2 + 1]) / focal[n * 2 + 1];
    const float* R  = Rm + n * 9;
    const float* Tc = Tv + n * 3;
    const float dwx = R[0] * dx + R[1] * dy + R[2];
    const float dwy = R[3] * dx + R[4] * dy + R[5];
    const float dwz = R[6] * dx + R[7] * dy + R[8];
    const float ox = -(Tc[0] * R[0] + Tc[1] * R[1] + Tc[2] * R[2]);
    const float oy = -(Tc[0] * R[3] + Tc[1] * R[4] + Tc[2] * R[5]);
    const float oz = -(Tc[0] * R[6] + Tc[1] * R[7] + Tc[2] * R[8]);

    // world -> grid coords: g = pt/VOXEL + (dim-1)/2  (VOL_TRANS = 0)
    const float inv_vox = 1.0f / VOXEL;
    const float bx = (VW - 1) * 0.5f;
    const float by = (VH - 1) * 0.5f;
    const float bz = (VD - 1) * 0.5f;
    const float dstep = (MAX_DEPTH - MIN_DEPTH) / (float)(NPTS - 1);

    float F0 = 0.f, F1 = 0.f, F2 = 0.f; // segment-local weighted color
    float A = 1.0f;                     // prod(1+EPS-d) over segment
    float P = 1.0f;                     // prod(1-d) over segment
    const int i0 = seg * SAMP_PER_SEG;
    const int S = VD * VH * VW;

    for (int k = 0; k < SAMP_PER_SEG; ++k) {
        const float depth = fmaf((float)(i0 + k), dstep, MIN_DEPTH);
        const float gx = fmaf(fmaf(depth, dwx, ox), inv_vox, bx);
        const float gy = fmaf(fmaf(depth, dwy, oy), inv_vox, by);
        const float gz = fmaf(fmaf(depth, dwz, oz), inv_vox, bz);

        float d = 0.f, r = 0.f, g = 0.f, b = 0.f;
        // fully-outside early-out: all 8 corners invalid or zero-weight
        if (gx > -1.f && gx < (float)VW &&
            gy > -1.f && gy < (float)VH &&
            gz > -1.f && gz < (float)VD) {
            const float x0f = floorf(gx), y0f = floorf(gy), z0f = floorf(gz);
            const float fx = gx - x0f, fy = gy - y0f, fz = gz - z0f;
            const int x0 = (int)x0f, y0 = (int)y0f, z0 = (int)z0f;
            #pragma unroll
            for (int c8 = 0; c8 < 8; ++c8) {
                const int dxl = c8 & 1, dyl = (c8 >> 1) & 1, dzl = c8 >> 2;
                const int xi = x0 + dxl, yi = y0 + dyl, zi = z0 + dzl;
                if (xi < 0 || xi >= VW || yi < 0 || yi >= VH || zi < 0 || zi >= VD)
                    continue;
                const float wt = (dxl ? fx : 1.f - fx) *
                                 (dyl ? fy : 1.f - fy) *
                                 (dzl ? fz : 1.f - fz);
                const int flat = (zi * VH + yi) * VW + xi;
                d = fmaf(dens[flat],         wt, d);
                r = fmaf(cols[flat],         wt, r);
                g = fmaf(cols[S + flat],     wt, g);
                b = fmaf(cols[2 * S + flat], wt, b);
            }
        }
        const float wgt = d * A;
        F0 = fmaf(wgt, r, F0);
        F1 = fmaf(wgt, g, F1);
        F2 = fmaf(wgt, b, F2);
        A *= (1.0f + EPS_T - d);
        P *= (1.0f - d);
    }

    // Combine 8 segments of this ray (lanes seg=0..7 within a group of 8).
    // Exclusive prefix product of A across the group:
    float incl = A;
    #pragma unroll
    for (int off = 1; off < SEG; off <<= 1) {
        float t = __shfl_up(incl, off, SEG);
        if (seg >= off) incl *= t;
    }
    float excl = __shfl_up(incl, 1, SEG);
    if (seg == 0) excl = 1.0f;

    float c0 = excl * F0, c1 = excl * F1, c2 = excl * F2;
    #pragma unroll
    for (int m = 1; m < SEG; m <<= 1) {
        c0 += __shfl_xor(c0, m, SEG);
        c1 += __shfl_xor(c1, m, SEG);
        c2 += __shfl_xor(c2, m, SEG);
        P  *= __shfl_xor(P, m, SEG);
    }

    float local_col = 0.f, local_sil = 0.f;
    if (seg == 0) {
        const float opac = 1.0f - P;
        local_sil = huber01(opac - tsil[pix]);
        const float* ti = timg + pix * 3;
        local_col = huber01(c0 - ti[0]) + huber01(c1 - ti[1]) + huber01(c2 - ti[2]);
    }

    // Wave (64) reduce, then LDS across 4 waves, one atomic per block.
    #pragma unroll
    for (int m = 1; m < 64; m <<= 1) {
        local_col += __shfl_xor(local_col, m, 64);
        local_sil += __shfl_xor(local_sil, m, 64);
    }
    __shared__ float sc[4], ss[4];
    const int wave = tid >> 6;
    if ((tid & 63) == 0) { sc[wave] = local_col; ss[wave] = local_sil; }
    __syncthreads();
    if (tid == 0) {
        float tcol = sc[0] + sc[1] + sc[2] + sc[3];
        float tsl  = ss[0] + ss[1] + ss[2] + ss[3];
        atomicAdd(&ws[0], tcol);
        atomicAdd(&ws[1], tsl);
    }
}

__global__ __launch_bounds__(256) void bev_kernel(
    const float* __restrict__ dens, float* __restrict__ ws)
{
    const int t = blockIdx.x * blockDim.x + threadIdx.x; // [0, VH*VW)
    float m = dens[t];
    #pragma unroll
    for (int z = 1; z < VD; ++z)
        m = fmaxf(m, dens[z * (VH * VW) + t]);
    float v = fabsf(m);
    #pragma unroll
    for (int msk = 1; msk < 64; msk <<= 1)
        v += __shfl_xor(v, msk, 64);
    __shared__ float sb[4];
    const int wave = threadIdx.x >> 6;
    if ((threadIdx.x & 63) == 0) sb[wave] = v;
    __syncthreads();
    if (threadIdx.x == 0)
        atomicAdd(&ws[2], sb[0] + sb[1] + sb[2] + sb[3]);
}

__global__ void finalize_kernel(const float* __restrict__ ws, float* __restrict__ out)
{
    if (threadIdx.x == 0) {
        out[0] = ws[0] / (float)(N_CAM * PH * PW * 3); // color_err
        out[1] = ws[1] / (float)(N_CAM * PH * PW);     // sil_err
        out[2] = ws[2] / (float)(VH * VW);             // bev_err
    }
}

extern "C" void kernel_launch(void* const* d_in, const int* in_sizes, int n_in,
                              void* d_out, int out_size, void* d_ws, size_t ws_size,
                              hipStream_t stream) {
    const float* dens      = (const float*)d_in[0];
    const float* cols      = (const float*)d_in[1];
    const float* tsil      = (const float*)d_in[2];
    const float* timg      = (const float*)d_in[3];
    const float* focal     = (const float*)d_in[4];
    const float* principal = (const float*)d_in[5];
    const float* Rm        = (const float*)d_in[6];
    const float* Tv        = (const float*)d_in[7];
    float* ws  = (float*)d_ws;
    float* out = (float*)d_out;

    hipMemsetAsync(ws, 0, 3 * sizeof(float), stream); // ws is poisoned each call

    render_loss_kernel<<<TOTAL_PIX / PIX_PER_BLOCK, 256, 0, stream>>>(
        dens, cols, tsil, timg, focal, principal, Rm, Tv, ws);
    bev_kernel<<<(VH * VW) / 256, 256, 0, stream>>>(dens, ws);
    finalize_kernel<<<1, 64, 0, stream>>>(ws, out);
}